// Round 1
// baseline (1092.517 us; speedup 1.0000x reference)
//
#include <hip/hip_runtime.h>
#include <math.h>

#define TT 250
#define BT 256
#define HN 128
#define ON 20
#define KIN 700

// ws layout (float offsets)
#define XIN_OFF 0            // 250*256*128 = 8192000 floats
#define W22_OFF 8192000      // 16384 floats (premasked w_h2h2)
#define ZROW_OFF 8208384     // 128 floats of zeros (dummy prefetch target)
// total 8208512 floats = 32.83 MB

// ---------------------------------------------------------------------------
// prep: w22m = w_h2h2 * mask[1]; zero the dummy row
// ---------------------------------------------------------------------------
__global__ __launch_bounds__(256) void prep_kernel(const float* __restrict__ w_h2h2,
                                                   const float* __restrict__ mask,
                                                   float* __restrict__ ws) {
    int i = blockIdx.x * 256 + threadIdx.x;
    if (i < HN * HN) ws[W22_OFF + i] = w_h2h2[i] * mask[HN * HN + i];
    int z = i - HN * HN;
    if (z >= 0 && z < HN) ws[ZROW_OFF + z] = 0.f;
}

// ---------------------------------------------------------------------------
// input projection: xin[t][b][h] = x[b][t][:] @ w_ih1[:,h] + b_ih1[h]
// M=64000 (rows b*250+t), K=700, N=128. 64-row x 128-col tile, BK=20.
// ---------------------------------------------------------------------------
__global__ __launch_bounds__(256) void gemm_in(const float* __restrict__ x,
                                               const float* __restrict__ w,
                                               const float* __restrict__ bias,
                                               float* __restrict__ xin) {
    __shared__ __align__(16) float As[20 * 68];   // [kk][row], pad 68 for banks
    __shared__ __align__(16) float Ws[20 * 128];  // [kk][col]
    const int tid = threadIdx.x;
    const int m0 = blockIdx.x * 64;
    const int r0 = (tid >> 5) * 8;     // 8 row-groups of 8 rows
    const int c0 = (tid & 31) * 4;     // 32 col-groups of 4 cols

    float4 acc[8];
#pragma unroll
    for (int r = 0; r < 8; r++) { acc[r].x = 0.f; acc[r].y = 0.f; acc[r].z = 0.f; acc[r].w = 0.f; }

    for (int k0 = 0; k0 < KIN; k0 += 20) {
        __syncthreads();
#pragma unroll
        for (int i = 0; i < 5; i++) {
            int idx = tid + i * 256;          // < 1280
            int row = idx / 20, kk = idx % 20;
            As[kk * 68 + row] = x[(m0 + row) * KIN + k0 + kk];
        }
#pragma unroll
        for (int i = 0; i < 10; i++) Ws[tid + i * 256] = w[k0 * 128 + tid + i * 256];
        __syncthreads();

#pragma unroll
        for (int kk = 0; kk < 20; kk++) {
            float4 wv = *(const float4*)&Ws[kk * 128 + c0];
            float a[8];
            *(float4*)&a[0] = *(const float4*)&As[kk * 68 + r0];
            *(float4*)&a[4] = *(const float4*)&As[kk * 68 + r0 + 4];
#pragma unroll
            for (int r = 0; r < 8; r++) {
                acc[r].x += a[r] * wv.x; acc[r].y += a[r] * wv.y;
                acc[r].z += a[r] * wv.z; acc[r].w += a[r] * wv.w;
            }
        }
    }

    const float4 bv = *(const float4*)&bias[c0];
#pragma unroll
    for (int r = 0; r < 8; r++) {
        int m = m0 + r0 + r;
        int t = m % TT, bb = m / TT;
        float4 o;
        o.x = acc[r].x + bv.x; o.y = acc[r].y + bv.y;
        o.z = acc[r].z + bv.z; o.w = acc[r].w + bv.w;
        *(float4*)&xin[(t * BT + bb) * HN + c0] = o;
    }
}

// ---------------------------------------------------------------------------
// recurrent scan: one block (128 thr, 2 waves) per batch row.
// Spikes are {0,1} -> recurrent matvecs are exact sparse f32 row-sums keyed
// by ballot bitmasks. w11/w12 in LDS f32; w22 rows register-prefetched from
// L2 (mask known one step ahead). All sparse loops batch independent loads.
// ---------------------------------------------------------------------------
__device__ __forceinline__ unsigned long long rfl64(unsigned long long v) {
    unsigned lo = (unsigned)__builtin_amdgcn_readfirstlane((int)(unsigned)v);
    unsigned hi = (unsigned)__builtin_amdgcn_readfirstlane((int)(unsigned)(v >> 32));
    return ((unsigned long long)hi << 32) | lo;
}

// batched sparse column sum from LDS (stride elems per source row)
__device__ __forceinline__ float sparse_sum_lds(const float* __restrict__ wl, int stride,
                                                const float* __restrict__ zl,
                                                unsigned long long m0, unsigned long long m1,
                                                int j) {
    float acc = 0.f;
    while (m0 | m1) {
        float pg[8];
#pragma unroll
        for (int i = 0; i < 8; i++) {
            const float* p;
            if (m0)      { int h = __builtin_ctzll(m0); m0 &= m0 - 1; p = wl + h * stride; }
            else if (m1) { int h = __builtin_ctzll(m1); m1 &= m1 - 1; p = wl + (h + 64) * stride; }
            else p = zl;
            pg[i] = p[j];
        }
        acc += ((pg[0] + pg[1]) + (pg[2] + pg[3])) + ((pg[4] + pg[5]) + (pg[6] + pg[7]));
    }
    return acc;
}

__global__ __launch_bounds__(128) void snn_scan(
    const float* __restrict__ xin, const float* __restrict__ w22m,
    const float* __restrict__ zrow, const float* __restrict__ mask,
    const float* __restrict__ w_h1h1, const float* __restrict__ b_h1h1,
    const float* __restrict__ w_h1h2, const float* __restrict__ b_h1h2,
    const float* __restrict__ b_h2h2, const float* __restrict__ w_h2o,
    const float* __restrict__ b_h2o, const float* __restrict__ tau_adp1,
    const float* __restrict__ tau_adp2, const float* __restrict__ taum1,
    const float* __restrict__ taum2, const float* __restrict__ taumo,
    const float* __restrict__ h1m0, const float* __restrict__ h2m0,
    const float* __restrict__ om0, float* __restrict__ out) {
    extern __shared__ float smem[];
    float* w11s = smem;            // 16384
    float* w12s = smem + 16384;    // 16384
    float* whos = smem + 32768;    // 2560
    float* omsh = smem + 35328;    // 32
    float* redsh = smem + 35360;   // 8
    unsigned long long* m1sh = (unsigned long long*)(smem + 35368); // 2
    unsigned long long* m2sh = (unsigned long long*)(smem + 35372); // 2
    float* zlds = smem + 35376;    // 128 zeros  -> total 35504 floats = 142016 B

    const int j = threadIdx.x;
    const int b = blockIdx.x;

    float pn = 0.f;  // A-norm partial (block 0 only)
    for (int i = j; i < HN * HN; i += HN) {
        float v = w_h1h1[i] * mask[i];
        w11s[i] = v;
        w12s[i] = w_h1h2[i];
        if (b == 0) pn += fabsf(v) + fabsf(w22m[i]);
    }
    for (int i = j; i < HN * ON; i += HN) whos[i] = w_h2o[i];
    zlds[j] = 0.f;

    const float a1 = expf(-1.f / taum1[j]);
    const float r1 = expf(-1.f / tau_adp1[j]);
    const float a2 = expf(-1.f / taum2[j]);
    const float r2 = expf(-1.f / tau_adp2[j]);
    const float bj11 = b_h1h1[j];
    const float bj12 = b_h1h2[j];
    const float bj22 = b_h2h2[j];
    const float ao  = expf(-1.f / taumo[j < ON ? j : 0]);
    const float bjo = b_h2o[j < ON ? j : 0];

    float h1m = h1m0[b * HN + j];
    float h2m = h2m0[b * HN + j];
    float om  = (j < ON) ? om0[b * ON + j] : 0.f;
    float b1 = 0.01f, b2 = 0.01f;
    float h1s = 0.f, h2s = 0.f;
    float s1c = 0.f, s2c = 0.f;
    float accj = 0.f;

    unsigned long long m1p0 = 0, m1p1 = 0, m2p0 = 0, m2p1 = 0;

    __syncthreads();

    float xt = xin[b * HN + j];

    for (int t = 0; t < TT; t++) {
        // prefetch next step's input (hide HBM latency across the step)
        const int tn = (t < TT - 1) ? t + 1 : t;
        const float xnext = xin[(tn * BT + b) * HN + j];

        // prefetch w22 rows for mask2_prev (up to 16, independent L2 loads)
        unsigned long long mm0 = m2p0, mm1 = m2p1;
        float pf[16];
#pragma unroll
        for (int i = 0; i < 16; i++) {
            const float* p;
            if (mm0)      { int h = __builtin_ctzll(mm0); mm0 &= mm0 - 1; p = w22m + (h << 7); }
            else if (mm1) { int h = __builtin_ctzll(mm1); mm1 &= mm1 - 1; p = w22m + ((h + 64) << 7); }
            else p = zrow;
            pf[i] = p[j];
        }

        // ---- layer 1 (adaptive LIF) ----
        float i1 = xt + bj11 + sparse_sum_lds(w11s, HN, zlds, m1p0, m1p1, j);
        b1 = r1 * b1 + (1.f - r1) * h1s;
        const float B1 = 0.01f + 1.8f * b1;
        h1m = a1 * h1m + (1.f - a1) * i1 - B1 * h1s;
        const float sp1 = (h1m - B1 > 0.f) ? 1.f : 0.f;
        h1s = sp1;
        s1c += sp1;

        unsigned long long bal1 = __ballot(sp1 > 0.f);
        if ((j & 63) == 0) m1sh[j >> 6] = bal1;
        __syncthreads();  // B1: exchange layer-1 spike masks
        const unsigned long long m1n0 = rfl64(m1sh[0]);
        const unsigned long long m1n1 = rfl64(m1sh[1]);

        // ---- layer 2 input ----
        float i2 = bj12 + bj22 + sparse_sum_lds(w12s, HN, zlds, m1n0, m1n1, j);
        {
            float sa = 0.f, sb = 0.f, sc = 0.f, sd = 0.f;
#pragma unroll
            for (int i = 0; i < 16; i += 4) { sa += pf[i]; sb += pf[i + 1]; sc += pf[i + 2]; sd += pf[i + 3]; }
            i2 += (sa + sb) + (sc + sd);
            while (mm0 | mm1) {  // overflow rows (pop2 > 16), batched
                float pg[8];
#pragma unroll
                for (int i = 0; i < 8; i++) {
                    const float* p;
                    if (mm0)      { int h = __builtin_ctzll(mm0); mm0 &= mm0 - 1; p = w22m + (h << 7); }
                    else if (mm1) { int h = __builtin_ctzll(mm1); mm1 &= mm1 - 1; p = w22m + ((h + 64) << 7); }
                    else p = zrow;
                    pg[i] = p[j];
                }
                i2 += ((pg[0] + pg[1]) + (pg[2] + pg[3])) + ((pg[4] + pg[5]) + (pg[6] + pg[7]));
            }
        }

        // ---- layer 2 (adaptive LIF) ----
        b2 = r2 * b2 + (1.f - r2) * h2s;
        const float B2 = 0.01f + 1.8f * b2;
        h2m = a2 * h2m + (1.f - a2) * i2 - B2 * h2s;
        const float sp2 = (h2m - B2 > 0.f) ? 1.f : 0.f;
        h2s = sp2;
        s2c += sp2;

        unsigned long long bal2 = __ballot(sp2 > 0.f);
        if ((j & 63) == 0) m2sh[j >> 6] = bal2;
        __syncthreads();  // B2: exchange layer-2 spike masks
        const unsigned long long m2n0 = rfl64(m2sh[0]);
        const unsigned long long m2n1 = rfl64(m2sh[1]);

        // ---- readout ----
        if (j < ON) {
            float io = bjo + sparse_sum_lds(whos, ON, zlds, m2n0, m2n1, j);
            om = ao * om + (1.f - ao) * io;
        }

        if (t > 10) {
            if (j < ON) omsh[j] = om;
            __syncthreads();  // B3: share om for softmax
            if (j < ON) {
                float mx = omsh[0];
#pragma unroll
                for (int k = 1; k < ON; k++) mx = fmaxf(mx, omsh[k]);
                float se = 0.f;
#pragma unroll
                for (int k = 0; k < ON; k++) se += __expf(omsh[k] - mx);
                accj += __expf(om - mx) / se;
            }
        }

        m1p0 = m1n0; m1p1 = m1n1;
        m2p0 = m2n0; m2p1 = m2n1;
        xt = xnext;
    }

    // outputs: [acc 256x20][s1 256x128][s2 256x128][A_norm]
    out[5120 + b * HN + j] = s1c * (1.f / 250.f);
    out[5120 + 32768 + b * HN + j] = s2c * (1.f / 250.f);
    if (j < ON) out[b * ON + j] = accj;

    if (b == 0) {
#pragma unroll
        for (int off = 32; off > 0; off >>= 1) pn += __shfl_down(pn, off);
        if ((j & 63) == 0) redsh[j >> 6] = pn;
        __syncthreads();
        if (j == 0) out[70656] = redsh[0] + redsh[1];
    }
}

// ---------------------------------------------------------------------------
extern "C" void kernel_launch(void* const* d_in, const int* in_sizes, int n_in,
                              void* d_out, int out_size, void* d_ws, size_t ws_size,
                              hipStream_t stream) {
    const float* x        = (const float*)d_in[0];
    const float* mask     = (const float*)d_in[1];
    const float* w_ih1    = (const float*)d_in[2];
    const float* b_ih1    = (const float*)d_in[3];
    const float* w_h1h1   = (const float*)d_in[4];
    const float* b_h1h1   = (const float*)d_in[5];
    const float* w_h1h2   = (const float*)d_in[6];
    const float* b_h1h2   = (const float*)d_in[7];
    const float* w_h2h2   = (const float*)d_in[8];
    const float* b_h2h2   = (const float*)d_in[9];
    const float* w_h2o    = (const float*)d_in[10];
    const float* b_h2o    = (const float*)d_in[11];
    const float* tau_adp1 = (const float*)d_in[12];
    const float* tau_adp2 = (const float*)d_in[13];
    const float* taum1    = (const float*)d_in[14];
    const float* taum2    = (const float*)d_in[15];
    const float* taumo    = (const float*)d_in[16];
    const float* h1m0     = (const float*)d_in[17];
    const float* h2m0     = (const float*)d_in[18];
    const float* om0      = (const float*)d_in[19];
    float* out = (float*)d_out;
    float* ws  = (float*)d_ws;

    float* xin  = ws + XIN_OFF;
    float* w22m = ws + W22_OFF;
    float* zrow = ws + ZROW_OFF;

    prep_kernel<<<65, 256, 0, stream>>>(w_h2h2, mask, ws);
    gemm_in<<<1000, 256, 0, stream>>>(x, w_ih1, b_ih1, xin);

    hipFuncSetAttribute(reinterpret_cast<const void*>(snn_scan),
                        hipFuncAttributeMaxDynamicSharedMemorySize, 142016);
    snn_scan<<<256, 128, 142016, stream>>>(xin, w22m, zrow, mask, w_h1h1, b_h1h1,
                                           w_h1h2, b_h1h2, b_h2h2, w_h2o, b_h2o,
                                           tau_adp1, tau_adp2, taum1, taum2, taumo,
                                           h1m0, h2m0, om0, out);
}